// Round 10
// baseline (429.866 us; speedup 1.0000x reference)
//
#include <hip/hip_runtime.h>

#define NROWS 16384   // B*L
#define LSEQ  2048
#define NB    8

typedef short v8s __attribute__((ext_vector_type(8)));
typedef float v4f __attribute__((ext_vector_type(4)));

__device__ __forceinline__ unsigned short f2bf(float f) {
    unsigned int u = __float_as_uint(f);
    return (unsigned short)((u + 0x7fffu + ((u >> 16) & 1u)) >> 16);
}
__device__ __forceinline__ float bf2f(unsigned short u) {
    return __uint_as_float(((unsigned int)u) << 16);
}

// fast exact-GELU: Abramowitz-Stegun 5-term erf, |err|<1.5e-7
__device__ __forceinline__ float fast_gelu(float v) {
    float z = fabsf(v) * 0.70710678118654752f;
    float t = __builtin_amdgcn_rcpf(1.0f + 0.3275911f * z);
    float poly = t * (0.254829592f + t * (-0.284496736f + t * (1.421413741f +
                 t * (-1.453152027f + t * 1.061405429f))));
    float erfz = 1.0f - poly * __expf(-z * z);
    float er = copysignf(erfz, v);
    return 0.5f * v * (1.0f + er);
}
__device__ __forceinline__ float fast_tanh(float y) {
    float e = __expf(2.0f * y);
    return (e - 1.0f) * __builtin_amdgcn_rcpf(e + 1.0f);
}

// ------- merged setup: embed+LN0 (blocks 0..4095) | weight transposes (4096..6239)
//         | class converts (6240..6242) -------
__global__ __launch_bounds__(256) void setup_kernel(
        const int* __restrict__ ids,
        const float* __restrict__ tok, const float* __restrict__ pos,
        const float* __restrict__ g0, const float* __restrict__ b0,
        unsigned short* __restrict__ x, unsigned short* __restrict__ hl,
        const float* __restrict__ w1, const float* __restrict__ w2,
        const float* __restrict__ wa, const float* __restrict__ wb, const float* __restrict__ wc,
        const float* __restrict__ ca, const float* __restrict__ cb, const float* __restrict__ cc,
        unsigned short* __restrict__ w1T, unsigned short* __restrict__ w2T,
        unsigned short* __restrict__ wabcT, unsigned short* __restrict__ clsb) {
    int blk = blockIdx.x;
    int t = threadIdx.x;
    if (blk < 4096) {
        int wave = t >> 6, lane = t & 63;
        long row = (long)blk * 4 + wave;
        int l = (int)(row & (LSEQ - 1));
        int id = ids[row];
        int d = lane * 8;
        float4 t0 = *(const float4*)(tok + (size_t)id * 512 + d);
        float4 t1 = *(const float4*)(tok + (size_t)id * 512 + d + 4);
        float4 p0 = *(const float4*)(pos + (size_t)l * 512 + d);
        float4 p1 = *(const float4*)(pos + (size_t)l * 512 + d + 4);
        float a[8] = {t0.x + p0.x, t0.y + p0.y, t0.z + p0.z, t0.w + p0.w,
                      t1.x + p1.x, t1.y + p1.y, t1.z + p1.z, t1.w + p1.w};
        unsigned int xp[4];
        #pragma unroll
        for (int i = 0; i < 4; ++i)
            xp[i] = (unsigned int)f2bf(a[2 * i]) | ((unsigned int)f2bf(a[2 * i + 1]) << 16);
        *(uint4*)(x + row * 512 + d) = *(uint4*)xp;
        float s = 0.f, s2 = 0.f;
        #pragma unroll
        for (int i = 0; i < 8; ++i) { s += a[i]; s2 += a[i] * a[i]; }
        #pragma unroll
        for (int o = 32; o > 0; o >>= 1) { s += __shfl_down(s, o); s2 += __shfl_down(s2, o); }
        s = __shfl(s, 0); s2 = __shfl(s2, 0);
        float m = s * (1.0f / 512.0f);
        float rinv = 1.0f / sqrtf(s2 * (1.0f / 512.0f) - m * m + 1e-5f);
        float4 ga = *(const float4*)(g0 + d), gb = *(const float4*)(g0 + d + 4);
        float4 ba = *(const float4*)(b0 + d), bb2 = *(const float4*)(b0 + d + 4);
        float gg[8] = {ga.x, ga.y, ga.z, ga.w, gb.x, gb.y, gb.z, gb.w};
        float bb[8] = {ba.x, ba.y, ba.z, ba.w, bb2.x, bb2.y, bb2.z, bb2.w};
        unsigned int hp[4];
        #pragma unroll
        for (int i = 0; i < 4; ++i) {
            unsigned short lo = f2bf((a[2 * i]     - m) * rinv * gg[2 * i]     + bb[2 * i]);
            unsigned short hi = f2bf((a[2 * i + 1] - m) * rinv * gg[2 * i + 1] + bb[2 * i + 1]);
            hp[i] = (unsigned int)lo | ((unsigned int)hi << 16);
        }
        *(uint4*)(hl + row * 512 + d) = *(uint4*)hp;
    } else if (blk < 6240) {
        int id = blk - 4096;
        int tx = t & 31, ty = t >> 5;
        const float* in; unsigned short* out; int R, C, bx, by, ldo;
        if (id < 1024) {
            int l = id >> 9, r = id & 511;
            in = w1 + l * 524288; out = w1T + l * 524288;
            R = 512; C = 1024; bx = r & 31; by = r >> 5; ldo = 512;
        } else if (id < 2048) {
            int l = (id - 1024) >> 9, r = (id - 1024) & 511;
            in = w2 + l * 524288; out = w2T + l * 524288;
            R = 1024; C = 512; bx = r & 15; by = r >> 4; ldo = 1024;
        } else {
            int g = (id - 2048) >> 5, r = (id - 2048) & 31;
            in = (g == 0) ? wa : (g == 1) ? wb : wc;
            out = wabcT + g * 32768;
            R = 512; C = 64; bx = r & 1; by = r >> 1; ldo = 512;
        }
        __shared__ unsigned short tile[32][33];
        int c0 = bx * 32, r0 = by * 32;
        for (int i = ty; i < 32; i += 8) {
            int r = r0 + i, c = c0 + tx;
            tile[i][tx] = (r < R && c < C) ? f2bf(in[(size_t)r * C + c]) : (unsigned short)0;
        }
        __syncthreads();
        for (int i = ty; i < 32; i += 8) {
            int c = c0 + i, r = r0 + tx;
            if (r < R && c < C) out[(size_t)c * ldo + r] = tile[tx][i];
        }
    } else {
        int g = blk - 6240;
        const float* src = (g == 0) ? ca : (g == 1) ? cb : cc;
        unsigned short* dst = clsb + g * 4096;
        for (int i = t; i < 4096; i += 256) dst[i] = f2bf(src[i]);
    }
}

// ------- LayerNorm, one wave per row -------
__global__ __launch_bounds__(256) void ln_kernel(const unsigned short* __restrict__ x,
        const float* __restrict__ g, const float* __restrict__ b,
        unsigned short* __restrict__ out) {
    int wave = threadIdx.x >> 6, lane = threadIdx.x & 63;
    long row = (long)blockIdx.x * 4 + wave;
    int d = lane * 8;
    uint4 xp = *(const uint4*)(x + row * 512 + d);
    const unsigned int* xw = (const unsigned int*)&xp;
    float a[8];
    #pragma unroll
    for (int i = 0; i < 4; ++i) {
        a[2 * i]     = bf2f((unsigned short)(xw[i] & 0xffff));
        a[2 * i + 1] = bf2f((unsigned short)(xw[i] >> 16));
    }
    float s = 0.f, s2 = 0.f;
    #pragma unroll
    for (int i = 0; i < 8; ++i) { s += a[i]; s2 += a[i] * a[i]; }
    #pragma unroll
    for (int o = 32; o > 0; o >>= 1) { s += __shfl_down(s, o); s2 += __shfl_down(s2, o); }
    s = __shfl(s, 0); s2 = __shfl(s2, 0);
    float m = s * (1.0f / 512.0f);
    float rinv = 1.0f / sqrtf(s2 * (1.0f / 512.0f) - m * m + 1e-5f);
    float4 g0 = *(const float4*)(g + d), g1 = *(const float4*)(g + d + 4);
    float4 b0 = *(const float4*)(b + d), b1 = *(const float4*)(b + d + 4);
    float gg[8] = {g0.x, g0.y, g0.z, g0.w, g1.x, g1.y, g1.z, g1.w};
    float bb[8] = {b0.x, b0.y, b0.z, b0.w, b1.x, b1.y, b1.z, b1.w};
    unsigned int hp[4];
    #pragma unroll
    for (int i = 0; i < 4; ++i) {
        unsigned short lo = f2bf((a[2 * i]     - m) * rinv * gg[2 * i]     + bb[2 * i]);
        unsigned short hi = f2bf((a[2 * i + 1] - m) * rinv * gg[2 * i + 1] + bb[2 * i + 1]);
        hp[i] = (unsigned int)lo | ((unsigned int)hi << 16);
    }
    *(uint4*)(out + row * 512 + d) = *(uint4*)hp;
}

// ------- MFMA GEMM: R2-winning 2-barrier K-loop, TM=128, TN = NJ*32 templated -------
// swapped-operand MFMA: per lane m fixed, n = wn + j*16 + quad*4 + reg (packed stores)
#define EPI_GELU_BF16  0
#define EPI_RES_BF16   1

template <int EPI, int NJ>
__global__ __launch_bounds__(256) void gemm_r2(
        const unsigned short* __restrict__ A, int lda,
        const unsigned short* __restrict__ BT, int ldb,
        const float* __restrict__ bias,
        const unsigned short* __restrict__ xres,
        unsigned short* __restrict__ Cout, int ldc, int K) {
    constexpr int TN = NJ * 32;
    constexpr int NBC = TN / 64;           // B staging chunks (64 rows each)
    __shared__ unsigned short As[128][40] __attribute__((aligned(16)));
    __shared__ unsigned short Bs[TN][40] __attribute__((aligned(16)));
    const int t = threadIdx.x;
    const int lane = t & 63, wave = t >> 6;
    const int quad = lane >> 4, l16 = lane & 15;
    const int wm = (wave >> 1) * 64, wn = (wave & 1) * (NJ * 16);
    const long tileM = (long)blockIdx.x * 128, tileN = (long)blockIdx.y * TN;
    const int arow = t >> 2, acol = (t & 3) * 8;

    const unsigned short* gA0 = A + (tileM + arow) * lda + acol;
    const unsigned short* gA1 = gA0 + 64 * (long)lda;
    const unsigned short* gB[NBC];
    #pragma unroll
    for (int c = 0; c < NBC; ++c)
        gB[c] = BT + (tileN + c * 64 + arow) * ldb + acol;

    v4f acc[4][NJ] = {};
    uint4 a0, a1, bb[NBC];

    a0 = *(const uint4*)gA0; a1 = *(const uint4*)gA1; gA0 += 32; gA1 += 32;
    #pragma unroll
    for (int c = 0; c < NBC; ++c) { bb[c] = *(const uint4*)gB[c]; gB[c] += 32; }
    *(uint4*)&As[arow][acol] = a0;
    *(uint4*)&As[arow + 64][acol] = a1;
    #pragma unroll
    for (int c = 0; c < NBC; ++c) *(uint4*)&Bs[c * 64 + arow][acol] = bb[c];

    const int nk = K >> 5;
    for (int kk = 0; kk < nk; ++kk) {
        __syncthreads();
        const bool more = kk + 1 < nk;
        if (more) {
            a0 = *(const uint4*)gA0; a1 = *(const uint4*)gA1; gA0 += 32; gA1 += 32;
            #pragma unroll
            for (int c = 0; c < NBC; ++c) { bb[c] = *(const uint4*)gB[c]; gB[c] += 32; }
        }
        v8s af[4], bfr[NJ];
        #pragma unroll
        for (int i = 0; i < 4; ++i) af[i] = *(const v8s*)&As[wm + i * 16 + l16][quad * 8];
        #pragma unroll
        for (int j = 0; j < NJ; ++j) bfr[j] = *(const v8s*)&Bs[wn + j * 16 + l16][quad * 8];
        #pragma unroll
        for (int i = 0; i < 4; ++i)
            #pragma unroll
            for (int j = 0; j < NJ; ++j)
                acc[i][j] = __builtin_amdgcn_mfma_f32_16x16x32_bf16(bfr[j], af[i], acc[i][j], 0, 0, 0);
        __syncthreads();
        if (more) {
            *(uint4*)&As[arow][acol] = a0;
            *(uint4*)&As[arow + 64][acol] = a1;
            #pragma unroll
            for (int c = 0; c < NBC; ++c) *(uint4*)&Bs[c * 64 + arow][acol] = bb[c];
        }
    }

    // packed epilogue: fixed m per lane, 4 consecutive n per acc
    #pragma unroll
    for (int i = 0; i < 4; ++i) {
        long m = tileM + wm + i * 16 + l16;
        #pragma unroll
        for (int j = 0; j < NJ; ++j) {
            long n0 = tileN + wn + j * 16 + quad * 4;
            float4 bi = *(const float4*)&bias[n0];
            const float* bip = (const float*)&bi;
            unsigned short pk[4];
            if (EPI == EPI_GELU_BF16) {
                #pragma unroll
                for (int r = 0; r < 4; ++r)
                    pk[r] = f2bf(fast_gelu(acc[i][j][r] + bip[r]));
            } else {
                ushort4 xr4 = *(const ushort4*)&xres[m * ldc + n0];
                const unsigned short* xp = (const unsigned short*)&xr4;
                #pragma unroll
                for (int r = 0; r < 4; ++r)
                    pk[r] = f2bf(acc[i][j][r] + bip[r] + bf2f(xp[r]));
            }
            *(ushort4*)&Cout[m * ldc + n0] = *(ushort4*)pk;
        }
    }
}

// ------- fused tanh-GEMM + class-GEMM, R2-structure K-loop, TM=128 -------
__global__ __launch_bounds__(256) void tanh_class_kernel(
        const unsigned short* __restrict__ A,
        const unsigned short* __restrict__ WT,
        const unsigned short* __restrict__ cls,
        unsigned short* __restrict__ uu) {
    __shared__ unsigned short As[128][40] __attribute__((aligned(16)));
    __shared__ unsigned short Bs[64][40] __attribute__((aligned(16)));
    __shared__ unsigned short P[128 * 72] __attribute__((aligned(16)));
    const int t = threadIdx.x;
    const int lane = t & 63, wave = t >> 6;
    const int quad = lane >> 4, l16 = lane & 15;
    const int wm = (wave >> 1) * 64, wn = (wave & 1) * 32;
    const long tileM = (long)blockIdx.x * 128;
    const int g = blockIdx.y;
    const int arow = t >> 2, acol = (t & 3) * 8;

    const unsigned short* BT = WT + g * 32768;
    v8s cf[2][2];
    #pragma unroll
    for (int ks = 0; ks < 2; ++ks)
        #pragma unroll
        for (int j = 0; j < 2; ++j)
            cf[ks][j] = *(const v8s*)&cls[g * 4096 + (wn + j * 16 + l16) * 64 + ks * 32 + quad * 8];

    const unsigned short* gA0 = A + (tileM + arow) * 512 + acol;
    const unsigned short* gA1 = gA0 + 64 * 512;
    const unsigned short* gB0 = BT + arow * 512 + acol;

    v4f acc[4][2] = {};
    uint4 a0, a1, b0;
    a0 = *(const uint4*)gA0; a1 = *(const uint4*)gA1; gA0 += 32; gA1 += 32;
    b0 = *(const uint4*)gB0; gB0 += 32;
    *(uint4*)&As[arow][acol] = a0;
    *(uint4*)&As[arow + 64][acol] = a1;
    *(uint4*)&Bs[arow][acol] = b0;

    for (int kk = 0; kk < 16; ++kk) {
        __syncthreads();
        const bool more = kk < 15;
        if (more) {
            a0 = *(const uint4*)gA0; a1 = *(const uint4*)gA1; gA0 += 32; gA1 += 32;
            b0 = *(const uint4*)gB0; gB0 += 32;
        }
        v8s af[4], bfr[2];
        #pragma unroll
        for (int i = 0; i < 4; ++i) af[i] = *(const v8s*)&As[wm + i * 16 + l16][quad * 8];
        #pragma unroll
        for (int j = 0; j < 2; ++j) bfr[j] = *(const v8s*)&Bs[wn + j * 16 + l16][quad * 8];
        #pragma unroll
        for (int i = 0; i < 4; ++i)
            #pragma unroll
            for (int j = 0; j < 2; ++j)
                acc[i][j] = __builtin_amdgcn_mfma_f32_16x16x32_bf16(bfr[j], af[i], acc[i][j], 0, 0, 0);
        __syncthreads();
        if (more) {
            *(uint4*)&As[arow][acol] = a0;
            *(uint4*)&As[arow + 64][acol] = a1;
            *(uint4*)&Bs[arow][acol] = b0;
        }
    }

    #pragma unroll
    for (int i = 0; i < 4; ++i) {
        int m = wm + i * 16 + l16;
        #pragma unroll
        for (int j = 0; j < 2; ++j) {
            int n0 = wn + j * 16 + quad * 4;
            unsigned short pk[4];
            #pragma unroll
            for (int r = 0; r < 4; ++r) pk[r] = f2bf(fast_tanh(acc[i][j][r]));
            *(ushort4*)&P[m * 72 + n0] = *(ushort4*)pk;
        }
    }
    __syncthreads();

    v4f acc2[4][2] = {};
    #pragma unroll
    for (int ks = 0; ks < 2; ++ks) {
        v8s paf[4];
        #pragma unroll
        for (int i = 0; i < 4; ++i)
            paf[i] = *(const v8s*)&P[(wm + i * 16 + l16) * 72 + ks * 32 + quad * 8];
        #pragma unroll
        for (int i = 0; i < 4; ++i)
            #pragma unroll
            for (int j = 0; j < 2; ++j)
                acc2[i][j] = __builtin_amdgcn_mfma_f32_16x16x32_bf16(cf[ks][j], paf[i], acc2[i][j], 0, 0, 0);
    }

    #pragma unroll
    for (int i = 0; i < 4; ++i) {
        long m = tileM + wm + i * 16 + l16;
        #pragma unroll
        for (int j = 0; j < 2; ++j) {
            int c0 = wn + j * 16 + quad * 4;
            unsigned short pk[4];
            #pragma unroll
            for (int r = 0; r < 4; ++r) pk[r] = f2bf(acc2[i][j][r]);
            *(ushort4*)&uu[m * 192 + g * 64 + c0] = *(ushort4*)pk;
        }
    }
}

// ------- exact ordered-triplet scan pass 1 -------
__global__ __launch_bounds__(64) void scan_part_kernel(const unsigned short* __restrict__ u,
                                                       float* __restrict__ part) {
    int b = blockIdx.x, seg = blockIdx.y;
    int c = threadIdx.x;
    int l0 = seg * 32;
    int l1 = l0 + 32; if (l1 > 2047) l1 = 2047;
    float sA = 0.f, sB = 0.f, sC = 0.f, T = 0.f, M = 0.f, U = 0.f;
    const unsigned short* base = u + ((size_t)b * LSEQ + l0) * 192 + c;
    for (int l = l0; l < l1; ++l) {
        float ua = bf2f(base[0]), ub = bf2f(base[64]), uc = bf2f(base[128]);
        base += 192;
        U += uc * T;
        M += uc * sB;
        T += ub * sA;
        sA += ua; sB += ub; sC += uc;
    }
    float* p = part + ((size_t)(b * 64 + seg)) * 384 + c;
    p[0] = sA; p[64] = sB; p[128] = sC; p[192] = T; p[256] = M; p[320] = U;
}

// ------- merged: segment combine + final LN + Wq GEMV -------
__global__ __launch_bounds__(64) void combine_final_kernel(const float* __restrict__ part,
        const unsigned short* __restrict__ x,
        const float* __restrict__ qw, const float* __restrict__ qb,
        const float* __restrict__ Wq, const float* __restrict__ bq,
        float* __restrict__ out, float inv_denom) {
    int b = blockIdx.x;
    int c = threadIdx.x;
    const float* p = part + (size_t)b * 64 * 384 + c;
    float A = p[0], B = p[64], Tt = p[192], Mt = p[256], Ut = p[320];
    for (int seg = 1; seg < 64; ++seg) {
        const float* q2 = p + seg * 384;
        float a2 = q2[0], b2 = q2[64], c2 = q2[128], t2 = q2[192], m2 = q2[256], u2 = q2[320];
        float Un = Ut + u2 + c2 * Tt + A * m2;
        float Tn = Tt + t2 + A * b2;
        float Mn = Mt + m2 + B * c2;
        A += a2; B += b2;
        Ut = Un; Tt = Tn; Mt = Mn;
    }
    __shared__ float q[512];
    __shared__ float mv[2];
    const unsigned short* xr = x + ((size_t)b * LSEQ + (LSEQ - 1)) * 512;
    float s1 = 0.f, s2 = 0.f;
    for (int i = c; i < 512; i += 64) { float v = bf2f(xr[i]); q[i] = v; s1 += v; s2 += v * v; }
    #pragma unroll
    for (int o = 32; o > 0; o >>= 1) { s1 += __shfl_down(s1, o); s2 += __shfl_down(s2, o); }
    if (c == 0) {
        float m = s1 * (1.0f / 512.0f);
        float var = s2 * (1.0f / 512.0f) - m * m;
        mv[0] = m; mv[1] = 1.0f / sqrtf(var + 1e-5f);
    }
    __syncthreads();
    float m = mv[0], r = mv[1];
    for (int i = c; i < 512; i += 64) q[i] = (q[i] - m) * r * qw[i] + qb[i];
    __syncthreads();
    float acc = 0.f;
    for (int d = 0; d < 512; ++d) acc += q[d] * Wq[d * 64 + c];
    out[b * 64 + c] = Ut * inv_denom + acc + bq[c];
}

extern "C" void kernel_launch(void* const* d_in, const int* in_sizes, int n_in,
                              void* d_out, int out_size, void* d_ws, size_t ws_size,
                              hipStream_t stream) {
    const int*   token_ids   = (const int*)d_in[0];
    const float* tok_emb     = (const float*)d_in[1];
    const float* pos_emb     = (const float*)d_in[2];
    const float* stem_ln_w   = (const float*)d_in[3];
    const float* stem_ln_b   = (const float*)d_in[4];
    const float* stem_w1     = (const float*)d_in[5];
    const float* stem_b1     = (const float*)d_in[6];
    const float* stem_w2     = (const float*)d_in[7];
    const float* stem_b2     = (const float*)d_in[8];
    const float* role_ln_w   = (const float*)d_in[9];
    const float* role_ln_b   = (const float*)d_in[10];
    const float* Wa          = (const float*)d_in[11];
    const float* Wb          = (const float*)d_in[12];
    const float* Wc          = (const float*)d_in[13];
    const float* class_a     = (const float*)d_in[14];
    const float* class_b     = (const float*)d_in[15];
    const float* class_c     = (const float*)d_in[16];
    const float* query_ln_w  = (const float*)d_in[17];
    const float* query_ln_b  = (const float*)d_in[18];
    const float* Wq          = (const float*)d_in[19];
    const float* bq          = (const float*)d_in[20];
    float* out = (float*)d_out;

    char* wsb = (char*)d_ws;
    unsigned short* x    = (unsigned short*)(wsb);              // 16,777,216
    unsigned short* hl   = (unsigned short*)(wsb + 16777216);   // 16,777,216
    unsigned short* Hb   = (unsigned short*)(wsb + 33554432);   // 33,554,432
    unsigned short* uu   = (unsigned short*)(wsb + 67108864);   // 6,291,456
    float* part          = (float*)(wsb + 73400320);            // 786,432
    unsigned short* w1T  = (unsigned short*)(wsb + 74188800);   // 2,097,152
    unsigned short* w2T  = (unsigned short*)(wsb + 76285952);   // 2,097,152
    unsigned short* wabcT= (unsigned short*)(wsb + 78383104);   // 196,608
    unsigned short* clsb = (unsigned short*)(wsb + 78579712);   // 24,576

    setup_kernel<<<6243, 256, 0, stream>>>(token_ids, tok_emb, pos_emb,
        stem_ln_w, stem_ln_b, x, hl,
        stem_w1, stem_w2, Wa, Wb, Wc, class_a, class_b, class_c,
        w1T, w2T, wabcT, clsb);

    for (int i = 0; i < 2; ++i) {
        if (i > 0)
            ln_kernel<<<NROWS / 4, 256, 0, stream>>>(x, stem_ln_w + 512, stem_ln_b + 512, hl);
        // w1: TN=256 (NJ=8), grid (128,4) — longer compute window per barrier interval
        gemm_r2<EPI_GELU_BF16, 8><<<dim3(128, 4), 256, 0, stream>>>(
            hl, 512, w1T + i * 524288, 512, stem_b1 + i * 1024, nullptr, Hb, 1024, 512);
        // w2: TN=128 (NJ=4), grid (128,4), K=1024
        gemm_r2<EPI_RES_BF16, 4><<<dim3(128, 4), 256, 0, stream>>>(
            Hb, 1024, w2T + i * 524288, 1024, stem_b2 + i * 512, x, x, 512, 1024);
    }

    ln_kernel<<<NROWS / 4, 256, 0, stream>>>(x, role_ln_w, role_ln_b, hl);

    tanh_class_kernel<<<dim3(128, 3), 256, 0, stream>>>(hl, wabcT, clsb, uu);

    scan_part_kernel<<<dim3(NB, 64), 64, 0, stream>>>(uu, part);

    float inv_denom = (float)(6.0 / (2047.0 * 2046.0 * 2045.0));
    combine_final_kernel<<<NB, 64, 0, stream>>>(part, x, query_ln_w, query_ln_b,
                                                Wq, bq, out, inv_denom);
}

// Round 11
// 340.299 us; speedup vs baseline: 1.2632x; 1.2632x over previous
//
#include <hip/hip_runtime.h>

#define NROWS 16384   // B*L
#define LSEQ  2048
#define NB    8

typedef short v8s __attribute__((ext_vector_type(8)));
typedef float v4f __attribute__((ext_vector_type(4)));

__device__ __forceinline__ unsigned short f2bf(float f) {
    unsigned int u = __float_as_uint(f);
    return (unsigned short)((u + 0x7fffu + ((u >> 16) & 1u)) >> 16);
}
__device__ __forceinline__ float bf2f(unsigned short u) {
    return __uint_as_float(((unsigned int)u) << 16);
}

// fast exact-GELU: Abramowitz-Stegun 5-term erf, |err|<1.5e-7
__device__ __forceinline__ float fast_gelu(float v) {
    float z = fabsf(v) * 0.70710678118654752f;
    float t = __builtin_amdgcn_rcpf(1.0f + 0.3275911f * z);
    float poly = t * (0.254829592f + t * (-0.284496736f + t * (1.421413741f +
                 t * (-1.453152027f + t * 1.061405429f))));
    float erfz = 1.0f - poly * __expf(-z * z);
    float er = copysignf(erfz, v);
    return 0.5f * v * (1.0f + er);
}
__device__ __forceinline__ float fast_tanh(float y) {
    float e = __expf(2.0f * y);
    return (e - 1.0f) * __builtin_amdgcn_rcpf(e + 1.0f);
}

// XCD row-swizzle: block b (of 4096, 4 rows each) -> rows of 128-row tile T with
// T%8 == b%8, so the producer's XCD matches the GEMM reader's XCD (= (m>>7)%8).
__device__ __forceinline__ long swizzled_row(int b, int wave) {
    int T = (b & 7) + (((b >> 3) & 15) << 3);   // 0..127, T%8 == b%8
    int chunk = b >> 7;                          // 0..31
    return (long)T * 128 + chunk * 4 + wave;
}

// ------- merged setup: embed (blocks 0..4095, XCD-swizzled) | weight transposes
//         (4096..6239) | class converts (6240..6242); embed also emits LN0(hl) -------
__global__ __launch_bounds__(256) void setup_kernel(
        const int* __restrict__ ids,
        const float* __restrict__ tok, const float* __restrict__ pos,
        const float* __restrict__ g0, const float* __restrict__ b0,
        unsigned short* __restrict__ x, unsigned short* __restrict__ hl,
        const float* __restrict__ w1, const float* __restrict__ w2,
        const float* __restrict__ wa, const float* __restrict__ wb, const float* __restrict__ wc,
        const float* __restrict__ ca, const float* __restrict__ cb, const float* __restrict__ cc,
        unsigned short* __restrict__ w1T, unsigned short* __restrict__ w2T,
        unsigned short* __restrict__ wabcT, unsigned short* __restrict__ clsb) {
    int blk = blockIdx.x;
    int t = threadIdx.x;
    if (blk < 4096) {
        int wave = t >> 6, lane = t & 63;
        long row = swizzled_row(blk, wave);
        int l = (int)(row & (LSEQ - 1));
        int id = ids[row];
        int d = lane * 8;
        float4 t0 = *(const float4*)(tok + (size_t)id * 512 + d);
        float4 t1 = *(const float4*)(tok + (size_t)id * 512 + d + 4);
        float4 p0 = *(const float4*)(pos + (size_t)l * 512 + d);
        float4 p1 = *(const float4*)(pos + (size_t)l * 512 + d + 4);
        float a[8] = {t0.x + p0.x, t0.y + p0.y, t0.z + p0.z, t0.w + p0.w,
                      t1.x + p1.x, t1.y + p1.y, t1.z + p1.z, t1.w + p1.w};
        unsigned int xp[4];
        #pragma unroll
        for (int i = 0; i < 4; ++i)
            xp[i] = (unsigned int)f2bf(a[2 * i]) | ((unsigned int)f2bf(a[2 * i + 1]) << 16);
        *(uint4*)(x + row * 512 + d) = *(uint4*)xp;
        float s = 0.f, s2 = 0.f;
        #pragma unroll
        for (int i = 0; i < 8; ++i) { s += a[i]; s2 += a[i] * a[i]; }
        #pragma unroll
        for (int o = 32; o > 0; o >>= 1) { s += __shfl_down(s, o); s2 += __shfl_down(s2, o); }
        s = __shfl(s, 0); s2 = __shfl(s2, 0);
        float m = s * (1.0f / 512.0f);
        float rinv = 1.0f / sqrtf(s2 * (1.0f / 512.0f) - m * m + 1e-5f);
        float4 ga = *(const float4*)(g0 + d), gb = *(const float4*)(g0 + d + 4);
        float4 ba = *(const float4*)(b0 + d), bb2 = *(const float4*)(b0 + d + 4);
        float gg[8] = {ga.x, ga.y, ga.z, ga.w, gb.x, gb.y, gb.z, gb.w};
        float bb[8] = {ba.x, ba.y, ba.z, ba.w, bb2.x, bb2.y, bb2.z, bb2.w};
        unsigned int hp[4];
        #pragma unroll
        for (int i = 0; i < 4; ++i) {
            unsigned short lo = f2bf((a[2 * i]     - m) * rinv * gg[2 * i]     + bb[2 * i]);
            unsigned short hi = f2bf((a[2 * i + 1] - m) * rinv * gg[2 * i + 1] + bb[2 * i + 1]);
            hp[i] = (unsigned int)lo | ((unsigned int)hi << 16);
        }
        *(uint4*)(hl + row * 512 + d) = *(uint4*)hp;
    } else if (blk < 6240) {
        int id = blk - 4096;
        int tx = t & 31, ty = t >> 5;
        const float* in; unsigned short* out; int R, C, bx, by, ldo;
        if (id < 1024) {
            int l = id >> 9, r = id & 511;
            in = w1 + l * 524288; out = w1T + l * 524288;
            R = 512; C = 1024; bx = r & 31; by = r >> 5; ldo = 512;
        } else if (id < 2048) {
            int l = (id - 1024) >> 9, r = (id - 1024) & 511;
            in = w2 + l * 524288; out = w2T + l * 524288;
            R = 1024; C = 512; bx = r & 15; by = r >> 4; ldo = 1024;
        } else {
            int g = (id - 2048) >> 5, r = (id - 2048) & 31;
            in = (g == 0) ? wa : (g == 1) ? wb : wc;
            out = wabcT + g * 32768;
            R = 512; C = 64; bx = r & 1; by = r >> 1; ldo = 512;
        }
        __shared__ unsigned short tile[32][33];
        int c0 = bx * 32, r0 = by * 32;
        for (int i = ty; i < 32; i += 8) {
            int r = r0 + i, c = c0 + tx;
            tile[i][tx] = (r < R && c < C) ? f2bf(in[(size_t)r * C + c]) : (unsigned short)0;
        }
        __syncthreads();
        for (int i = ty; i < 32; i += 8) {
            int c = c0 + i, r = r0 + tx;
            if (r < R && c < C) out[(size_t)c * ldo + r] = tile[tx][i];
        }
    } else {
        int g = blk - 6240;
        const float* src = (g == 0) ? ca : (g == 1) ? cb : cc;
        unsigned short* dst = clsb + g * 4096;
        for (int i = t; i < 4096; i += 256) dst[i] = f2bf(src[i]);
    }
}

// ------- LayerNorm, one wave per row, XCD-swizzled block->row mapping -------
__global__ __launch_bounds__(256) void ln_kernel(const unsigned short* __restrict__ x,
        const float* __restrict__ g, const float* __restrict__ b,
        unsigned short* __restrict__ out) {
    int wave = threadIdx.x >> 6, lane = threadIdx.x & 63;
    long row = swizzled_row(blockIdx.x, wave);
    int d = lane * 8;
    uint4 xp = *(const uint4*)(x + row * 512 + d);
    const unsigned int* xw = (const unsigned int*)&xp;
    float a[8];
    #pragma unroll
    for (int i = 0; i < 4; ++i) {
        a[2 * i]     = bf2f((unsigned short)(xw[i] & 0xffff));
        a[2 * i + 1] = bf2f((unsigned short)(xw[i] >> 16));
    }
    float s = 0.f, s2 = 0.f;
    #pragma unroll
    for (int i = 0; i < 8; ++i) { s += a[i]; s2 += a[i] * a[i]; }
    #pragma unroll
    for (int o = 32; o > 0; o >>= 1) { s += __shfl_down(s, o); s2 += __shfl_down(s2, o); }
    s = __shfl(s, 0); s2 = __shfl(s2, 0);
    float m = s * (1.0f / 512.0f);
    float rinv = 1.0f / sqrtf(s2 * (1.0f / 512.0f) - m * m + 1e-5f);
    float4 g0 = *(const float4*)(g + d), g1 = *(const float4*)(g + d + 4);
    float4 b0 = *(const float4*)(b + d), b1 = *(const float4*)(b + d + 4);
    float gg[8] = {g0.x, g0.y, g0.z, g0.w, g1.x, g1.y, g1.z, g1.w};
    float bb[8] = {b0.x, b0.y, b0.z, b0.w, b1.x, b1.y, b1.z, b1.w};
    unsigned int hp[4];
    #pragma unroll
    for (int i = 0; i < 4; ++i) {
        unsigned short lo = f2bf((a[2 * i]     - m) * rinv * gg[2 * i]     + bb[2 * i]);
        unsigned short hi = f2bf((a[2 * i + 1] - m) * rinv * gg[2 * i + 1] + bb[2 * i + 1]);
        hp[i] = (unsigned int)lo | ((unsigned int)hi << 16);
    }
    *(uint4*)(out + row * 512 + d) = *(uint4*)hp;
}

// ------- MFMA GEMM: R2 2-barrier structure + swapped-operand packed epilogue -------
// (exact 343-µs configuration)
#define EPI_GELU_BF16  0
#define EPI_RES_BF16   1

template <int EPI, int TN>
__global__ __launch_bounds__(256) void gemm_r2(
        const unsigned short* __restrict__ A, int lda,
        const unsigned short* __restrict__ BT, int ldb,
        const float* __restrict__ bias,
        const unsigned short* __restrict__ xres,
        unsigned short* __restrict__ Cout, int ldc, int K) {
    constexpr int NJ = TN / 32;
    __shared__ unsigned short As[128][40] __attribute__((aligned(16)));
    __shared__ unsigned short Bs[TN][40] __attribute__((aligned(16)));
    const int t = threadIdx.x;
    const int lane = t & 63, wave = t >> 6;
    const int quad = lane >> 4, l16 = lane & 15;
    const int wm = (wave >> 1) * 64, wn = (wave & 1) * (TN / 2);
    const long tileM = (long)blockIdx.x * 128, tileN = (long)blockIdx.y * TN;
    const int arow = t >> 2, acol = (t & 3) * 8;

    const unsigned short* gA0 = A + (tileM + arow) * lda + acol;
    const unsigned short* gA1 = gA0 + 64 * (long)lda;
    const unsigned short* gB0 = BT + (tileN + arow) * ldb + acol;
    const unsigned short* gB1 = gB0 + 64 * (long)ldb;

    v4f acc[4][NJ] = {};
    uint4 a0, a1, b0, b1;

    a0 = *(const uint4*)gA0; a1 = *(const uint4*)gA1; gA0 += 32; gA1 += 32;
    b0 = *(const uint4*)gB0; gB0 += 32;
    if (TN == 128) { b1 = *(const uint4*)gB1; gB1 += 32; }
    *(uint4*)&As[arow][acol] = a0;
    *(uint4*)&As[arow + 64][acol] = a1;
    *(uint4*)&Bs[arow][acol] = b0;
    if (TN == 128) *(uint4*)&Bs[arow + 64][acol] = b1;

    const int nk = K >> 5;
    for (int kk = 0; kk < nk; ++kk) {
        __syncthreads();
        const bool more = kk + 1 < nk;
        if (more) {
            a0 = *(const uint4*)gA0; a1 = *(const uint4*)gA1; gA0 += 32; gA1 += 32;
            b0 = *(const uint4*)gB0; gB0 += 32;
            if (TN == 128) { b1 = *(const uint4*)gB1; gB1 += 32; }
        }
        v8s af[4], bfr[NJ];
        #pragma unroll
        for (int i = 0; i < 4; ++i) af[i] = *(const v8s*)&As[wm + i * 16 + l16][quad * 8];
        #pragma unroll
        for (int j = 0; j < NJ; ++j) bfr[j] = *(const v8s*)&Bs[wn + j * 16 + l16][quad * 8];
        #pragma unroll
        for (int i = 0; i < 4; ++i)
            #pragma unroll
            for (int j = 0; j < NJ; ++j)
                acc[i][j] = __builtin_amdgcn_mfma_f32_16x16x32_bf16(bfr[j], af[i], acc[i][j], 0, 0, 0);
        __syncthreads();
        if (more) {
            *(uint4*)&As[arow][acol] = a0;
            *(uint4*)&As[arow + 64][acol] = a1;
            *(uint4*)&Bs[arow][acol] = b0;
            if (TN == 128) *(uint4*)&Bs[arow + 64][acol] = b1;
        }
    }

    // packed epilogue: fixed m per lane, 4 consecutive n per acc
    #pragma unroll
    for (int i = 0; i < 4; ++i) {
        long m = tileM + wm + i * 16 + l16;
        #pragma unroll
        for (int j = 0; j < NJ; ++j) {
            long n0 = tileN + wn + j * 16 + quad * 4;
            float4 bi = *(const float4*)&bias[n0];
            const float* bip = (const float*)&bi;
            unsigned short pk[4];
            if (EPI == EPI_GELU_BF16) {
                #pragma unroll
                for (int r = 0; r < 4; ++r)
                    pk[r] = f2bf(fast_gelu(acc[i][j][r] + bip[r]));
            } else {
                ushort4 xr4 = *(const ushort4*)&xres[m * ldc + n0];
                const unsigned short* xp = (const unsigned short*)&xr4;
                #pragma unroll
                for (int r = 0; r < 4; ++r)
                    pk[r] = f2bf(acc[i][j][r] + bip[r] + bf2f(xp[r]));
            }
            *(ushort4*)&Cout[m * ldc + n0] = *(ushort4*)pk;
        }
    }
}

// ------- fused tanh-GEMM + class-GEMM, R2-structure K-loop, TM=128 -------
__global__ __launch_bounds__(256) void tanh_class_kernel(
        const unsigned short* __restrict__ A,
        const unsigned short* __restrict__ WT,
        const unsigned short* __restrict__ cls,
        unsigned short* __restrict__ uu) {
    __shared__ unsigned short As[128][40] __attribute__((aligned(16)));
    __shared__ unsigned short Bs[64][40] __attribute__((aligned(16)));
    __shared__ unsigned short P[128 * 72] __attribute__((aligned(16)));
    const int t = threadIdx.x;
    const int lane = t & 63, wave = t >> 6;
    const int quad = lane >> 4, l16 = lane & 15;
    const int wm = (wave >> 1) * 64, wn = (wave & 1) * 32;
    const long tileM = (long)blockIdx.x * 128;
    const int g = blockIdx.y;
    const int arow = t >> 2, acol = (t & 3) * 8;

    const unsigned short* BT = WT + g * 32768;
    v8s cf[2][2];
    #pragma unroll
    for (int ks = 0; ks < 2; ++ks)
        #pragma unroll
        for (int j = 0; j < 2; ++j)
            cf[ks][j] = *(const v8s*)&cls[g * 4096 + (wn + j * 16 + l16) * 64 + ks * 32 + quad * 8];

    const unsigned short* gA0 = A + (tileM + arow) * 512 + acol;
    const unsigned short* gA1 = gA0 + 64 * 512;
    const unsigned short* gB0 = BT + arow * 512 + acol;

    v4f acc[4][2] = {};
    uint4 a0, a1, b0;
    a0 = *(const uint4*)gA0; a1 = *(const uint4*)gA1; gA0 += 32; gA1 += 32;
    b0 = *(const uint4*)gB0; gB0 += 32;
    *(uint4*)&As[arow][acol] = a0;
    *(uint4*)&As[arow + 64][acol] = a1;
    *(uint4*)&Bs[arow][acol] = b0;

    for (int kk = 0; kk < 16; ++kk) {
        __syncthreads();
        const bool more = kk < 15;
        if (more) {
            a0 = *(const uint4*)gA0; a1 = *(const uint4*)gA1; gA0 += 32; gA1 += 32;
            b0 = *(const uint4*)gB0; gB0 += 32;
        }
        v8s af[4], bfr[2];
        #pragma unroll
        for (int i = 0; i < 4; ++i) af[i] = *(const v8s*)&As[wm + i * 16 + l16][quad * 8];
        #pragma unroll
        for (int j = 0; j < 2; ++j) bfr[j] = *(const v8s*)&Bs[wn + j * 16 + l16][quad * 8];
        #pragma unroll
        for (int i = 0; i < 4; ++i)
            #pragma unroll
            for (int j = 0; j < 2; ++j)
                acc[i][j] = __builtin_amdgcn_mfma_f32_16x16x32_bf16(bfr[j], af[i], acc[i][j], 0, 0, 0);
        __syncthreads();
        if (more) {
            *(uint4*)&As[arow][acol] = a0;
            *(uint4*)&As[arow + 64][acol] = a1;
            *(uint4*)&Bs[arow][acol] = b0;
        }
    }

    #pragma unroll
    for (int i = 0; i < 4; ++i) {
        int m = wm + i * 16 + l16;
        #pragma unroll
        for (int j = 0; j < 2; ++j) {
            int n0 = wn + j * 16 + quad * 4;
            unsigned short pk[4];
            #pragma unroll
            for (int r = 0; r < 4; ++r) pk[r] = f2bf(fast_tanh(acc[i][j][r]));
            *(ushort4*)&P[m * 72 + n0] = *(ushort4*)pk;
        }
    }
    __syncthreads();

    v4f acc2[4][2] = {};
    #pragma unroll
    for (int ks = 0; ks < 2; ++ks) {
        v8s paf[4];
        #pragma unroll
        for (int i = 0; i < 4; ++i)
            paf[i] = *(const v8s*)&P[(wm + i * 16 + l16) * 72 + ks * 32 + quad * 8];
        #pragma unroll
        for (int i = 0; i < 4; ++i)
            #pragma unroll
            for (int j = 0; j < 2; ++j)
                acc2[i][j] = __builtin_amdgcn_mfma_f32_16x16x32_bf16(cf[ks][j], paf[i], acc2[i][j], 0, 0, 0);
    }

    #pragma unroll
    for (int i = 0; i < 4; ++i) {
        long m = tileM + wm + i * 16 + l16;
        #pragma unroll
        for (int j = 0; j < 2; ++j) {
            int c0 = wn + j * 16 + quad * 4;
            unsigned short pk[4];
            #pragma unroll
            for (int r = 0; r < 4; ++r) pk[r] = f2bf(acc2[i][j][r]);
            *(ushort4*)&uu[m * 192 + g * 64 + c0] = *(ushort4*)pk;
        }
    }
}

// ------- exact ordered-triplet scan pass 1 -------
__global__ __launch_bounds__(64) void scan_part_kernel(const unsigned short* __restrict__ u,
                                                       float* __restrict__ part) {
    int b = blockIdx.x, seg = blockIdx.y;
    int c = threadIdx.x;
    int l0 = seg * 32;
    int l1 = l0 + 32; if (l1 > 2047) l1 = 2047;
    float sA = 0.f, sB = 0.f, sC = 0.f, T = 0.f, M = 0.f, U = 0.f;
    const unsigned short* base = u + ((size_t)b * LSEQ + l0) * 192 + c;
    for (int l = l0; l < l1; ++l) {
        float ua = bf2f(base[0]), ub = bf2f(base[64]), uc = bf2f(base[128]);
        base += 192;
        U += uc * T;
        M += uc * sB;
        T += ub * sA;
        sA += ua; sB += ub; sC += uc;
    }
    float* p = part + ((size_t)(b * 64 + seg)) * 384 + c;
    p[0] = sA; p[64] = sB; p[128] = sC; p[192] = T; p[256] = M; p[320] = U;
}

// ------- merged: segment combine + final LN + Wq GEMV -------
__global__ __launch_bounds__(64) void combine_final_kernel(const float* __restrict__ part,
        const unsigned short* __restrict__ x,
        const float* __restrict__ qw, const float* __restrict__ qb,
        const float* __restrict__ Wq, const float* __restrict__ bq,
        float* __restrict__ out, float inv_denom) {
    int b = blockIdx.x;
    int c = threadIdx.x;
    const float* p = part + (size_t)b * 64 * 384 + c;
    float A = p[0], B = p[64], Tt = p[192], Mt = p[256], Ut = p[320];
    for (int seg = 1; seg < 64; ++seg) {
        const float* q2 = p + seg * 384;
        float a2 = q2[0], b2 = q2[64], c2 = q2[128], t2 = q2[192], m2 = q2[256], u2 = q2[320];
        float Un = Ut + u2 + c2 * Tt + A * m2;
        float Tn = Tt + t2 + A * b2;
        float Mn = Mt + m2 + B * c2;
        A += a2; B += b2;
        Ut = Un; Tt = Tn; Mt = Mn;
    }
    __shared__ float q[512];
    __shared__ float mv[2];
    const unsigned short* xr = x + ((size_t)b * LSEQ + (LSEQ - 1)) * 512;
    float s1 = 0.f, s2 = 0.f;
    for (int i = c; i < 512; i += 64) { float v = bf2f(xr[i]); q[i] = v; s1 += v; s2 += v * v; }
    #pragma unroll
    for (int o = 32; o > 0; o >>= 1) { s1 += __shfl_down(s1, o); s2 += __shfl_down(s2, o); }
    if (c == 0) {
        float m = s1 * (1.0f / 512.0f);
        float var = s2 * (1.0f / 512.0f) - m * m;
        mv[0] = m; mv[1] = 1.0f / sqrtf(var + 1e-5f);
    }
    __syncthreads();
    float m = mv[0], r = mv[1];
    for (int i = c; i < 512; i += 64) q[i] = (q[i] - m) * r * qw[i] + qb[i];
    __syncthreads();
    float acc = 0.f;
    for (int d = 0; d < 512; ++d) acc += q[d] * Wq[d * 64 + c];
    out[b * 64 + c] = Ut * inv_denom + acc + bq[c];
}

extern "C" void kernel_launch(void* const* d_in, const int* in_sizes, int n_in,
                              void* d_out, int out_size, void* d_ws, size_t ws_size,
                              hipStream_t stream) {
    const int*   token_ids   = (const int*)d_in[0];
    const float* tok_emb     = (const float*)d_in[1];
    const float* pos_emb     = (const float*)d_in[2];
    const float* stem_ln_w   = (const float*)d_in[3];
    const float* stem_ln_b   = (const float*)d_in[4];
    const float* stem_w1     = (const float*)d_in[5];
    const float* stem_b1     = (const float*)d_in[6];
    const float* stem_w2     = (const float*)d_in[7];
    const float* stem_b2     = (const float*)d_in[8];
    const float* role_ln_w   = (const float*)d_in[9];
    const float* role_ln_b   = (const float*)d_in[10];
    const float* Wa          = (const float*)d_in[11];
    const float* Wb          = (const float*)d_in[12];
    const float* Wc          = (const float*)d_in[13];
    const float* class_a     = (const float*)d_in[14];
    const float* class_b     = (const float*)d_in[15];
    const float* class_c     = (const float*)d_in[16];
    const float* query_ln_w  = (const float*)d_in[17];
    const float* query_ln_b  = (const float*)d_in[18];
    const float* Wq          = (const float*)d_in[19];
    const float* bq          = (const float*)d_in[20];
    float* out = (float*)d_out;

    char* wsb = (char*)d_ws;
    unsigned short* x    = (unsigned short*)(wsb);              // 16,777,216
    unsigned short* hl   = (unsigned short*)(wsb + 16777216);   // 16,777,216
    unsigned short* Hb   = (unsigned short*)(wsb + 33554432);   // 33,554,432
    unsigned short* uu   = (unsigned short*)(wsb + 67108864);   // 6,291,456
    float* part          = (float*)(wsb + 73400320);            // 786,432
    unsigned short* w1T  = (unsigned short*)(wsb + 74188800);   // 2,097,152
    unsigned short* w2T  = (unsigned short*)(wsb + 76285952);   // 2,097,152
    unsigned short* wabcT= (unsigned short*)(wsb + 78383104);   // 196,608
    unsigned short* clsb = (unsigned short*)(wsb + 78579712);   // 24,576

    setup_kernel<<<6243, 256, 0, stream>>>(token_ids, tok_emb, pos_emb,
        stem_ln_w, stem_ln_b, x, hl,
        stem_w1, stem_w2, Wa, Wb, Wc, class_a, class_b, class_c,
        w1T, w2T, wabcT, clsb);

    for (int i = 0; i < 2; ++i) {
        if (i > 0)
            ln_kernel<<<NROWS / 4, 256, 0, stream>>>(x, stem_ln_w + 512, stem_ln_b + 512, hl);
        gemm_r2<EPI_GELU_BF16, 128><<<dim3(128, 8), 256, 0, stream>>>(
            hl, 512, w1T + i * 524288, 512, stem_b1 + i * 1024, nullptr, Hb, 1024, 512);
        gemm_r2<EPI_RES_BF16, 64><<<dim3(128, 8), 256, 0, stream>>>(
            Hb, 1024, w2T + i * 524288, 1024, stem_b2 + i * 512, x, x, 512, 1024);
    }

    ln_kernel<<<NROWS / 4, 256, 0, stream>>>(x, role_ln_w, role_ln_b, hl);

    tanh_class_kernel<<<dim3(128, 3), 256, 0, stream>>>(hl, wabcT, clsb, uu);

    scan_part_kernel<<<dim3(NB, 64), 64, 0, stream>>>(uu, part);

    float inv_denom = (float)(6.0 / (2047.0 * 2046.0 * 2045.0));
    combine_final_kernel<<<NB, 64, 0, stream>>>(part, x, query_ln_w, query_ln_b,
                                                Wq, bq, out, inv_denom);
}